// Round 16
// baseline (2852.110 us; speedup 1.0000x reference)
//
#include <hip/hip_runtime.h>
#include <hip/hip_bf16.h>
#include <math.h>

#define B_  256
#define L_  100
#define H_  384
#define NH_ 12
#define DH_ 32
#define NL_ 6
#define FF_ 1536
#define M_  (B_*L_)   // 25600 rows
#define QKVN 1152     // 3*H

// per-layer transposed bf16x2 weight layout within wT + l*LW (elements)
#define LW     3538944
#define OFF_Q  0
#define OFF_K  294912
#define OFF_V  589824
#define OFF_WO 884736
#define OFF_W1 1179648
#define OFF_W2 2359296

typedef __attribute__((ext_vector_type(8))) short short8;
typedef __attribute__((ext_vector_type(4))) float f32x4;

#define GLOBAL_AS __attribute__((address_space(1)))
#define LDS_AS    __attribute__((address_space(3)))

__device__ __forceinline__ void gload_lds16(const void* g, void* l) {
    __builtin_amdgcn_global_load_lds((const GLOBAL_AS void*)g, (LDS_AS void*)l, 16, 0, 0);
}

__device__ __forceinline__ void split2(float v, __hip_bfloat16& hi, __hip_bfloat16& lo) {
    hi = __float2bfloat16(v);
    lo = __float2bfloat16(v - __bfloat162float(hi));
}

__device__ __forceinline__ unsigned short f2b(float v) {
    __hip_bfloat16 h = __float2bfloat16(v);
    return *(unsigned short*)&h;
}

#define VMW(N) asm volatile("s_waitcnt vmcnt(" #N ")" ::: "memory")

// ---------------- embedding: acc2 = split(tok[x] + seg[s] + pos[l]) * nonpad -------
__global__ void embed_kernel(const int* __restrict__ x, const int* __restrict__ seg,
                             const float* __restrict__ tok, const float* __restrict__ sege,
                             const float* __restrict__ pos,
                             __hip_bfloat16* __restrict__ acc2) {
    int idx = blockIdx.x * blockDim.x + threadIdx.x;
    if (idx >= M_ * H_) return;
    int m = idx / H_;
    int f = idx - m * H_;
    int t = x[m];
    int s = seg[m];
    int l = m % L_;
    float v = tok[t * H_ + f] + sege[s * H_ + f] + pos[l * H_ + f];
    v = (t != 0) ? v : 0.0f;
    __hip_bfloat16 h, lo;
    split2(v, h, lo);
    acc2[(size_t)m * (2 * H_) + f]      = h;
    acc2[(size_t)m * (2 * H_) + H_ + f] = lo;
}

// ------ ALL-layers weight prep, hoisted (f32 -> bf16x2 [N][2K]), one launch --------
__global__ void transpose_all_kernel(const float* __restrict__ Wq, const float* __restrict__ Wk,
        const float* __restrict__ Wv, const float* __restrict__ Wo,
        const float* __restrict__ W1, const float* __restrict__ W2,
        __hip_bfloat16* __restrict__ wT) {
    __shared__ float tile[32][33];
    int l = blockIdx.x / 1728;
    int bid = blockIdx.x % 1728;
    const float* src;
    __hip_bfloat16* dst;
    int K, N, nx, tix, perm = 0;
    if (bid < 432) {               // Q,K,V: 3 x 144 tiles
        int m = bid / 144; tix = bid % 144;
        src = (m == 0) ? Wq : (m == 1 ? Wk : Wv);
        src += (size_t)l * H_ * H_;
        dst = wT + (size_t)l * LW + (m == 0 ? OFF_Q : (m == 1 ? OFF_K : OFF_V));
        K = 384; N = 384; nx = 12; perm = 1;
    } else if (bid < 576) {        // Wo: 144
        tix = bid - 432; src = Wo + (size_t)l * H_ * H_;
        dst = wT + (size_t)l * LW + OFF_WO; K = 384; N = 384; nx = 12;
    } else if (bid < 1152) {       // W1: 576
        tix = bid - 576; src = W1 + (size_t)l * H_ * FF_;
        dst = wT + (size_t)l * LW + OFF_W1; K = 384; N = 1536; nx = 48;
    } else {                       // W2: 576
        tix = bid - 1152; src = W2 + (size_t)l * FF_ * H_;
        dst = wT + (size_t)l * LW + OFF_W2; K = 1536; N = 384; nx = 12;
    }
    int n0 = (tix % nx) * 32, k0 = (tix / nx) * 32;
    int tx = threadIdx.x, ty = threadIdx.y;
    #pragma unroll
    for (int i = ty; i < 32; i += 8)
        tile[i][tx] = src[(size_t)(k0 + i) * N + (n0 + tx)];
    __syncthreads();
    #pragma unroll
    for (int i = ty; i < 32; i += 8) {
        float v = tile[tx][i];
        __hip_bfloat16 h, lo;
        split2(v, h, lo);
        int j = n0 + i;
        int jo = perm ? ((j % 12) * 32 + j / 12) : j;
        dst[(size_t)jo * (2 * K) + (k0 + tx)]     = h;
        dst[(size_t)jo * (2 * K) + K + (k0 + tx)] = lo;
    }
}

// bias concat with head-major permutation: out col j' = t*384 + nh*32 + d
__global__ void bias_concat_kernel(const float* __restrict__ bq, const float* __restrict__ bk,
                                   const float* __restrict__ bv, float* __restrict__ out) {
    int i = blockIdx.x * 256 + threadIdx.x;
    if (i >= NL_ * QKVN) return;
    int l = i / QKVN, jp = i - l * QKVN;
    int t = jp / 384, r = jp % 384;
    int h = r >> 5, d = r & 31;
    int j = d * 12 + h;  // original (interleaved) column
    float v = (t == 0) ? bq[l * 384 + j] : (t == 1 ? bk[l * 384 + j] : bv[l * 384 + j]);
    out[i] = v;
}

// ---- init out with bias (split-K W2 accumulates atomically on top) ----
__global__ void initw2_kernel(const float* __restrict__ bias, float* __restrict__ out) {
    int i = blockIdx.x * 256 + threadIdx.x;
    if (i < M_ * H_) out[i] = bias[i % H_];
}

// -------------------- split-precision MFMA GEMM (templated, proven R10) ------------
// MODEK 0: 3-term C = A_hi@W_hi + A_hi@W_lo + A_lo@W_hi ; A [M][2K], W [N][2K]; Kend=3K
// MODEK 2: 2-term C = A@(W_hi+W_lo)  (bf16-A x fp32-W)   ; A [M][K],  W [N][2K]; Kend=2K
// BIG=1: 256x128 tile, 8 waves. BIG=0: 128x128, 4 waves.
// SPLITK=1: grid doubled; each half covers Kend/2 and atomicAdds fp32 partials into
// a bias-pre-initialized output (2 commutative adds -> bitwise deterministic).
// 3-buffer LDS, 2-deep prefetch, counted vmcnt, raw s_barrier, setprio on MFMA.
template <int TAG, int BIG, int OMODE, int MODEK, int ACT, int SPLITK>
__global__ __launch_bounds__(BIG ? 512 : 256) void gemm_bf16_kernel(
        const __hip_bfloat16* __restrict__ A2,
        const __hip_bfloat16* __restrict__ Wt2,
        const float* __restrict__ bias,
        void* __restrict__ outp,
        int N, int K, int nbx) {
    constexpr int BM = BIG ? 256 : 128;
    __shared__ __hip_bfloat16 As[3][BM * 32];
    __shared__ __hip_bfloat16 Bs[3][128 * 32];
    int t = threadIdx.x;
    int lane = t & 63, wv = t >> 6;
    int wm = wv >> 1, wn = wv & 1;

    int nwg = gridDim.x;
    int q8 = nwg >> 3, r8 = nwg & 7;
    int xcd = blockIdx.x & 7, off = blockIdx.x >> 3;
    int swz = (xcd < r8 ? xcd * (q8 + 1) : r8 * (q8 + 1) + (xcd - r8) * q8) + off;
    int half = 0;
    if (SPLITK) {
        int nhalf = nwg >> 1;
        half = (swz >= nhalf) ? 1 : 0;
        swz -= half * nhalf;
    }
    int bn = (swz % nbx) * 128;
    int bm = (swz / nbx) * BM;

    const int KstA = (MODEK == 2) ? K : 2 * K;
    const int KstW = 2 * K;
    const int Kend = (MODEK == 0) ? 3 * K : 2 * K;
    f32x4 acc[4][4] = {};

    int sr   = t >> 2;
    int sswz = (t & 3) ^ ((t >> 2) & 3) ^ ((t >> 4) & 3);
    const __hip_bfloat16* a_src = A2 + (size_t)(bm + sr) * KstA + sswz * 8;
    const __hip_bfloat16* b_src = Wt2 + (size_t)(bn + sr) * KstW + sswz * 8;

    int slotp = (lane >> 4) ^ (lane & 3) ^ ((lane >> 2) & 3);
    int aOff = (wm * 64 + (lane & 15)) * 32 + slotp * 8;
    int bOff = (wn * 64 + (lane & 15)) * 32 + slotp * 8;

#define STAGE(buf, ak, wk) do { \
        gload_lds16(a_src + (ak), &As[buf][wv * 512]); \
        gload_lds16(a_src + (size_t)(BM / 2) * KstA + (ak), &As[buf][(BM / 2) * 32 + wv * 512]); \
        gload_lds16(b_src + (wk), &Bs[buf][wv * 512]); \
        if (!BIG) gload_lds16(b_src + (size_t)64 * KstW + (wk), &Bs[buf][2048 + wv * 512]); \
    } while (0)

#define KOFFS(k0, ak, wk) do { \
        if (MODEK == 0) { ak = ((k0) < K) ? (k0) : (k0) - K; wk = ((k0) < 2 * K) ? (k0) : (k0) - 2 * K; } \
        else            { ak = ((k0) < K) ? (k0) : (k0) - K; wk = (k0); } \
    } while (0)

    int nt = Kend >> 5;
    int nth = SPLITK ? (nt >> 1) : nt;          // steps this block runs
    int kb  = SPLITK ? half * (Kend >> 1) : 0;  // logical-K base
    {
        int ak, wk;
        KOFFS(kb, ak, wk);
        STAGE(0, ak, wk);
        KOFFS(kb + 32, ak, wk);
        STAGE(1, ak, wk);
    }
    int c0 = 0, c1 = 1, c2 = 2;
    for (int ti = 0; ti < nth; ++ti) {
        if (ti + 2 < nth) {
            int k2 = kb + ((ti + 2) << 5);
            int ak, wk;
            KOFFS(k2, ak, wk);
            STAGE(c2, ak, wk);
            if (BIG) { VMW(6); } else { VMW(8); }
        } else if (ti + 2 == nth) {
            if (BIG) { VMW(3); } else { VMW(4); }
        } else {
            VMW(0);
        }
        __builtin_amdgcn_s_barrier();
        short8 af[4], bf[4];
        #pragma unroll
        for (int m = 0; m < 4; ++m) af[m] = *(const short8*)(&As[c0][aOff + m * 512]);
        #pragma unroll
        for (int n = 0; n < 4; ++n) bf[n] = *(const short8*)(&Bs[c0][bOff + n * 512]);
        __builtin_amdgcn_s_setprio(1);
        #pragma unroll
        for (int m = 0; m < 4; ++m)
            #pragma unroll
            for (int n = 0; n < 4; ++n)
                acc[m][n] = __builtin_amdgcn_mfma_f32_16x16x32_bf16(af[m], bf[n], acc[m][n], 0, 0, 0);
        __builtin_amdgcn_s_setprio(0);
        __builtin_amdgcn_s_barrier();
        int tmp = c0; c0 = c1; c1 = c2; c2 = tmp;
    }
#undef STAGE
#undef KOFFS

    int colBase = bn + wn * 64 + (lane & 15);
    int rowBase = bm + wm * 64 + (lane >> 4) * 4;
    const float c0f = 0.7978845608f;
    #pragma unroll
    for (int n = 0; n < 4; ++n) {
        int c = colBase + n * 16;
        float bvv = SPLITK ? 0.0f : bias[c];
        #pragma unroll
        for (int m = 0; m < 4; ++m) {
            int r0 = rowBase + m * 16;
            #pragma unroll
            for (int r = 0; r < 4; ++r) {
                float v = acc[m][n][r] + bvv;
                if (ACT == 1) {
                    // gelu(v) = v*sigmoid(2u) == v*0.5*(1+tanh(u)); __expf form
                    float u = c0f * (v + 0.044715f * v * v * v);
                    v = v / (1.0f + __expf(-2.0f * u));
                }
                size_t row = (size_t)(r0 + r);
                if (SPLITK) {
                    atomicAdd(&((float*)outp)[row * N + c], v);
                } else if (OMODE == 0) {
                    ((float*)outp)[row * N + c] = v;
                } else {
                    ((__hip_bfloat16*)outp)[row * N + c] = __float2bfloat16(v);
                }
            }
        }
    }
}

// ---------------- MFMA attention per (b, nh) ----------------------------------------
__global__ __launch_bounds__(256) void attn_kernel(const __hip_bfloat16* __restrict__ qkvP,
        const int* __restrict__ x, __hip_bfloat16* __restrict__ a2) {
    __shared__ unsigned short qs[112][32];
    __shared__ unsigned short ks[128][32];
    __shared__ unsigned short vst[32][136];
    __shared__ unsigned short ps[112][136];
    __shared__ int xb[128];
    int t = threadIdx.x;
    int lane = t & 63, wv = t >> 6;
    int b = blockIdx.x / NH_;
    int nh = blockIdx.x % NH_;
    const __hip_bfloat16* base = qkvP + (size_t)b * L_ * QKVN;

    for (int i = t; i < 576; i += 256) {
        int d = i / 18, w = i % 18;
        ((int*)vst)[d * 68 + 50 + w] = 0;
    }
    for (int i = t; i < 128; i += 256) xb[i] = (i < L_) ? x[b * L_ + i] : 0;

    {
        int r16 = lane >> 2, s = lane & 3;
        for (int i = wv; i < 7; i += 4) {
            int row = i * 16 + r16;
            int sp = s ^ (row & 3) ^ ((row >> 2) & 3);
            gload_lds16(base + (size_t)row * QKVN + nh * 32 + sp * 8, &qs[i * 16][0]);
        }
        for (int i = wv; i < 8; i += 4) {
            int row = i * 16 + r16;
            int sp = s ^ (row & 3) ^ ((row >> 2) & 3);
            gload_lds16(base + (size_t)row * QKVN + 384 + nh * 32 + sp * 8, &ks[i * 16][0]);
        }
    }
    if (t < 200) {
        int kv = t >> 1, d0 = (t & 1) * 16;
        const __hip_bfloat16* vsrc = base + (size_t)kv * QKVN + 768 + nh * 32 + d0;
        short8 v0 = *(const short8*)vsrc;
        short8 v1 = *(const short8*)(vsrc + 8);
        #pragma unroll
        for (int j = 0; j < 8; ++j) {
            vst[d0 + j][kv]     = (unsigned short)v0[j];
            vst[d0 + 8 + j][kv] = (unsigned short)v1[j];
        }
    }
    __syncthreads();

    const float scale = 1.0f / sqrtf((float)H_);
    int n = lane & 15, g = lane >> 4;

    for (int rt = wv; rt < 7; rt += 4) {
        int arow = rt * 16 + n;
        int asp = (g ^ (arow & 3) ^ ((arow >> 2) & 3)) * 8;
        short8 aq = *(const short8*)&qs[arow][asp];
        f32x4 s8[8];
        #pragma unroll
        for (int ct = 0; ct < 8; ++ct) {
            int brow = ct * 16 + n;
            int bsp = (g ^ (brow & 3) ^ ((brow >> 2) & 3)) * 8;
            short8 bk = *(const short8*)&ks[brow][bsp];
            f32x4 z = {0.0f, 0.0f, 0.0f, 0.0f};
            s8[ct] = __builtin_amdgcn_mfma_f32_16x16x32_bf16(aq, bk, z, 0, 0, 0);
        }
        #pragma unroll
        for (int ct = 0; ct < 8; ++ct) {
            int col = ct * 16 + n;
            int xv = xb[col];
            #pragma unroll
            for (int r = 0; r < 4; ++r) {
                float v = s8[ct][r] * scale;
                v = (xv == 0) ? -1e10f : v;
                v = (col >= L_) ? -INFINITY : v;
                s8[ct][r] = v;
            }
        }
        float sm[4];
        #pragma unroll
        for (int r = 0; r < 4; ++r) {
            float m = s8[0][r];
            #pragma unroll
            for (int ct = 1; ct < 8; ++ct) m = fmaxf(m, s8[ct][r]);
            m = fmaxf(m, __shfl_xor(m, 1, 16));
            m = fmaxf(m, __shfl_xor(m, 2, 16));
            m = fmaxf(m, __shfl_xor(m, 4, 16));
            m = fmaxf(m, __shfl_xor(m, 8, 16));
            float s = 0.0f;
            #pragma unroll
            for (int ct = 0; ct < 8; ++ct) {
                float p = __expf(s8[ct][r] - m);
                s8[ct][r] = p;
                s += p;
            }
            s += __shfl_xor(s, 1, 16);
            s += __shfl_xor(s, 2, 16);
            s += __shfl_xor(s, 4, 16);
            s += __shfl_xor(s, 8, 16);
            sm[r] = s;
        }
        int prow = rt * 16 + g * 4;
        #pragma unroll
        for (int ct = 0; ct < 8; ++ct) {
            int col = ct * 16 + n;
            #pragma unroll
            for (int r = 0; r < 4; ++r)
                ps[prow + r][col] = f2b(s8[ct][r]);
        }
        f32x4 o0 = {0.0f, 0.0f, 0.0f, 0.0f}, o1 = o0;
        #pragma unroll
        for (int kt = 0; kt < 4; ++kt) {
            short8 pa = *(const short8*)&ps[rt * 16 + n][kt * 32 + g * 8];
            short8 b0 = *(const short8*)&vst[n][kt * 32 + g * 8];
            short8 b1 = *(const short8*)&vst[16 + n][kt * 32 + g * 8];
            o0 = __builtin_amdgcn_mfma_f32_16x16x32_bf16(pa, b0, o0, 0, 0, 0);
            o1 = __builtin_amdgcn_mfma_f32_16x16x32_bf16(pa, b1, o1, 0, 0, 0);
        }
        #pragma unroll
        for (int r = 0; r < 4; ++r) {
            int lrow = prow + r;
            if (lrow < L_) {
                size_t row = (size_t)b * L_ + lrow;
                float inv = 1.0f / sm[r];
                __hip_bfloat16 h, lo;
                float v0 = o0[r] * inv;
                split2(v0, h, lo);
                a2[row * (2 * H_) + nh * DH_ + n]      = h;
                a2[row * (2 * H_) + H_ + nh * DH_ + n] = lo;
                float v1 = o1[r] * inv;
                split2(v1, h, lo);
                a2[row * (2 * H_) + nh * DH_ + 16 + n]      = h;
                a2[row * (2 * H_) + H_ + nh * DH_ + 16 + n] = lo;
            }
        }
    }
}

// ---------------- fused residual + LayerNorm (scalar g,b; ddof=1) * nonpad ---------
template <int MODE>
__global__ __launch_bounds__(128) void ln_kernel(
        const float* __restrict__ Xf,
        const __hip_bfloat16* __restrict__ R2,
        const int* __restrict__ x,
        const float* __restrict__ gp, const float* __restrict__ bp, int layer,
        float* __restrict__ Yf,
        __hip_bfloat16* __restrict__ Y2,
        __hip_bfloat16* __restrict__ acc2) {
    int row = blockIdx.x;
    int tid = threadIdx.x;
    size_t b1 = (size_t)row * H_;
    size_t b2 = (size_t)row * (2 * H_);

    float v[3];
    #pragma unroll
    for (int j = 0; j < 3; ++j) {
        int f = tid + j * 128;
        float r = __bfloat162float(R2[b2 + f]) + __bfloat162float(R2[b2 + H_ + f]);
        v[j] = Xf[b1 + f] + r;
    }

    __shared__ float red[2];
    float s = v[0] + v[1] + v[2];
    #pragma unroll
    for (int off = 32; off > 0; off >>= 1) s += __shfl_down(s, off);
    if ((tid & 63) == 0) red[tid >> 6] = s;
    __syncthreads();
    float mu = (red[0] + red[1]) * (1.0f / 384.0f);
    __syncthreads();

    float d[3];
    float qq = 0.0f;
    #pragma unroll
    for (int j = 0; j < 3; ++j) { d[j] = v[j] - mu; qq += d[j] * d[j]; }
    #pragma unroll
    for (int off = 32; off > 0; off >>= 1) qq += __shfl_down(qq, off);
    if ((tid & 63) == 0) red[tid >> 6] = qq;
    __syncthreads();
    float var = (red[0] + red[1]) * (1.0f / 383.0f);
    float rstd = rsqrtf(var + 1e-8f);

    float g = gp[layer], bb = bp[layer];
    float np_ = (x[row] != 0) ? 1.0f : 0.0f;
    #pragma unroll
    for (int j = 0; j < 3; ++j) {
        int f = tid + j * 128;
        float y = (g * (d[j] * rstd) + bb) * np_;
        if (MODE == 0) {
            __hip_bfloat16 h, lo;
            split2(y, h, lo);
            Y2[b2 + f]      = h;
            Y2[b2 + H_ + f] = lo;
        } else {
            Yf[b1 + f] = y;
            float a = __bfloat162float(acc2[b2 + f]) + __bfloat162float(acc2[b2 + H_ + f]) + y;
            __hip_bfloat16 h, lo;
            split2(a, h, lo);
            acc2[b2 + f]      = h;
            acc2[b2 + H_ + f] = lo;
        }
    }
}

extern "C" void kernel_launch(void* const* d_in, const int* in_sizes, int n_in,
                              void* d_out, int out_size, void* d_ws, size_t ws_size,
                              hipStream_t stream) {
    const int*   x    = (const int*)d_in[0];
    const int*   seg  = (const int*)d_in[1];
    const float* tok  = (const float*)d_in[2];
    const float* sege = (const float*)d_in[3];
    const float* pos  = (const float*)d_in[4];
    const float* Wq   = (const float*)d_in[5];
    const float* bq   = (const float*)d_in[6];
    const float* Wk   = (const float*)d_in[7];
    const float* bk   = (const float*)d_in[8];
    const float* Wv   = (const float*)d_in[9];
    const float* bv   = (const float*)d_in[10];
    const float* Wo   = (const float*)d_in[11];
    const float* bo   = (const float*)d_in[12];
    const float* g1   = (const float*)d_in[13];
    const float* be1  = (const float*)d_in[14];
    const float* W1   = (const float*)d_in[15];
    const float* b1   = (const float*)d_in[16];
    const float* W2   = (const float*)d_in[17];
    const float* b2   = (const float*)d_in[18];
    const float* g2   = (const float*)d_in[19];
    const float* be2  = (const float*)d_in[20];

    char* p = (char*)d_ws;
    __hip_bfloat16* wT   = (__hip_bfloat16*)p; p += (size_t)NL_ * LW * 2;
    __hip_bfloat16* acc2 = (__hip_bfloat16*)p; p += 39321600;
    __hip_bfloat16* bE2  = (__hip_bfloat16*)p; p += 39321600;
    float* qkvb          = (float*)p;          p += 27648;
    char* pool           = p;
    __hip_bfloat16* qkvP = (__hip_bfloat16*)pool;
    __hip_bfloat16* bA2  = (__hip_bfloat16*)(pool + 58982400);
    float*          woF  = (float*)pool;
    __hip_bfloat16* f2   = (__hip_bfloat16*)pool;
    float* out = (float*)d_out;

    transpose_all_kernel<<<dim3(1728 * NL_), dim3(32, 8), 0, stream>>>(Wq, Wk, Wv, Wo, W1, W2, wT);
    bias_concat_kernel<<<dim3((NL_ * QKVN + 255) / 256), dim3(256), 0, stream>>>(bq, bk, bv, qkvb);
    embed_kernel<<<dim3((M_ * H_ + 255) / 256), dim3(256), 0, stream>>>(x, seg, tok, sege, pos, acc2);

    for (int l = 0; l < NL_; ++l) {
        const __hip_bfloat16* wTL = wT + (size_t)l * LW;
        const float* bol = bo + (size_t)l * H_;
        const float* b1l = b1 + (size_t)l * FF_;
        const float* b2l = b2 + (size_t)l * H_;

        // QKV (head-major cols), 3-term -> qkvP bf16 : BIG, 900 blocks
        gemm_bf16_kernel<0, 1, 2, 0, 0, 0><<<dim3((QKVN / 128) * (M_ / 256)), dim3(512), 0, stream>>>(
            acc2, wTL + OFF_Q, qkvb + (size_t)l * QKVN, qkvP, QKVN, H_, QKVN / 128);
        // MFMA attention -> bA2 bf16x2
        attn_kernel<<<dim3(B_ * NH_), dim3(256), 0, stream>>>(qkvP, x, bA2);
        // Wo, 3-term (f32 output) -> woF : 128x128 (600 blocks)
        gemm_bf16_kernel<1, 0, 0, 0, 0, 0><<<dim3((H_ / 128) * (M_ / 128)), dim3(256), 0, stream>>>(
            bA2, wTL + OFF_WO, bol, woF, H_, H_, H_ / 128);
        // LN1(woF + acc2) -> bE2
        ln_kernel<0><<<dim3(M_), dim3(128), 0, stream>>>(
            woF, acc2, x, g1, be1, l, nullptr, bE2, nullptr);
        // W1, 3-term + gelu -> f2 bf16 : BIG (R10-proven), 1200 blocks
        gemm_bf16_kernel<2, 1, 2, 0, 1, 0><<<dim3((FF_ / 128) * (M_ / 256)), dim3(512), 0, stream>>>(
            bE2, wTL + OFF_W1, b1l, f2, FF_, H_, FF_ / 128);
        // W2: out = bias (init) then 2-way split-K atomic accumulate : 1200 blocks
        initw2_kernel<<<dim3((M_ * H_ + 255) / 256), dim3(256), 0, stream>>>(b2l, out);
        gemm_bf16_kernel<3, 0, 0, 2, 0, 1><<<dim3(2 * (H_ / 128) * (M_ / 128)), dim3(256), 0, stream>>>(
            f2, wTL + OFF_W2, b2l, out, H_, FF_, H_ / 128);
        // LN2(out + bE2) -> out ; acc2 update
        ln_kernel<1><<<dim3(M_), dim3(128), 0, stream>>>(
            out, bE2, x, g2, be2, l, out, nullptr, acc2);
    }
}

// Round 17
// 2535.565 us; speedup vs baseline: 1.1248x; 1.1248x over previous
//
#include <hip/hip_runtime.h>
#include <hip/hip_bf16.h>
#include <math.h>

#define B_  256
#define L_  100
#define H_  384
#define NH_ 12
#define DH_ 32
#define NL_ 6
#define FF_ 1536
#define M_  (B_*L_)   // 25600 rows
#define QKVN 1152     // 3*H

// per-layer transposed bf16x2 weight layout within wT + l*LW (elements)
#define LW     3538944
#define OFF_Q  0
#define OFF_K  294912
#define OFF_V  589824
#define OFF_WO 884736
#define OFF_W1 1179648
#define OFF_W2 2359296

typedef __attribute__((ext_vector_type(8))) short short8;
typedef __attribute__((ext_vector_type(4))) float f32x4;

#define GLOBAL_AS __attribute__((address_space(1)))
#define LDS_AS    __attribute__((address_space(3)))

__device__ __forceinline__ void gload_lds16(const void* g, void* l) {
    __builtin_amdgcn_global_load_lds((const GLOBAL_AS void*)g, (LDS_AS void*)l, 16, 0, 0);
}

__device__ __forceinline__ void split2(float v, __hip_bfloat16& hi, __hip_bfloat16& lo) {
    hi = __float2bfloat16(v);
    lo = __float2bfloat16(v - __bfloat162float(hi));
}

__device__ __forceinline__ unsigned short f2b(float v) {
    __hip_bfloat16 h = __float2bfloat16(v);
    return *(unsigned short*)&h;
}

#define VMW(N) asm volatile("s_waitcnt vmcnt(" #N ")" ::: "memory")

// ---------------- embedding: acc2 = split(tok[x] + seg[s] + pos[l]) * nonpad -------
__global__ void embed_kernel(const int* __restrict__ x, const int* __restrict__ seg,
                             const float* __restrict__ tok, const float* __restrict__ sege,
                             const float* __restrict__ pos,
                             __hip_bfloat16* __restrict__ acc2) {
    int idx = blockIdx.x * blockDim.x + threadIdx.x;
    if (idx >= M_ * H_) return;
    int m = idx / H_;
    int f = idx - m * H_;
    int t = x[m];
    int s = seg[m];
    int l = m % L_;
    float v = tok[t * H_ + f] + sege[s * H_ + f] + pos[l * H_ + f];
    v = (t != 0) ? v : 0.0f;
    __hip_bfloat16 h, lo;
    split2(v, h, lo);
    acc2[(size_t)m * (2 * H_) + f]      = h;
    acc2[(size_t)m * (2 * H_) + H_ + f] = lo;
}

// ------ ALL-layers weight prep, hoisted (f32 -> bf16x2 [N][2K]), one launch --------
__global__ void transpose_all_kernel(const float* __restrict__ Wq, const float* __restrict__ Wk,
        const float* __restrict__ Wv, const float* __restrict__ Wo,
        const float* __restrict__ W1, const float* __restrict__ W2,
        __hip_bfloat16* __restrict__ wT) {
    __shared__ float tile[32][33];
    int l = blockIdx.x / 1728;
    int bid = blockIdx.x % 1728;
    const float* src;
    __hip_bfloat16* dst;
    int K, N, nx, tix, perm = 0;
    if (bid < 432) {               // Q,K,V: 3 x 144 tiles
        int m = bid / 144; tix = bid % 144;
        src = (m == 0) ? Wq : (m == 1 ? Wk : Wv);
        src += (size_t)l * H_ * H_;
        dst = wT + (size_t)l * LW + (m == 0 ? OFF_Q : (m == 1 ? OFF_K : OFF_V));
        K = 384; N = 384; nx = 12; perm = 1;
    } else if (bid < 576) {        // Wo: 144
        tix = bid - 432; src = Wo + (size_t)l * H_ * H_;
        dst = wT + (size_t)l * LW + OFF_WO; K = 384; N = 384; nx = 12;
    } else if (bid < 1152) {       // W1: 576
        tix = bid - 576; src = W1 + (size_t)l * H_ * FF_;
        dst = wT + (size_t)l * LW + OFF_W1; K = 384; N = 1536; nx = 48;
    } else {                       // W2: 576
        tix = bid - 1152; src = W2 + (size_t)l * FF_ * H_;
        dst = wT + (size_t)l * LW + OFF_W2; K = 1536; N = 384; nx = 12;
    }
    int n0 = (tix % nx) * 32, k0 = (tix / nx) * 32;
    int tx = threadIdx.x, ty = threadIdx.y;
    #pragma unroll
    for (int i = ty; i < 32; i += 8)
        tile[i][tx] = src[(size_t)(k0 + i) * N + (n0 + tx)];
    __syncthreads();
    #pragma unroll
    for (int i = ty; i < 32; i += 8) {
        float v = tile[tx][i];
        __hip_bfloat16 h, lo;
        split2(v, h, lo);
        int j = n0 + i;
        int jo = perm ? ((j % 12) * 32 + j / 12) : j;
        dst[(size_t)jo * (2 * K) + (k0 + tx)]     = h;
        dst[(size_t)jo * (2 * K) + K + (k0 + tx)] = lo;
    }
}

// bias concat with head-major permutation: out col j' = t*384 + nh*32 + d
__global__ void bias_concat_kernel(const float* __restrict__ bq, const float* __restrict__ bk,
                                   const float* __restrict__ bv, float* __restrict__ out) {
    int i = blockIdx.x * 256 + threadIdx.x;
    if (i >= NL_ * QKVN) return;
    int l = i / QKVN, jp = i - l * QKVN;
    int t = jp / 384, r = jp % 384;
    int h = r >> 5, d = r & 31;
    int j = d * 12 + h;  // original (interleaved) column
    float v = (t == 0) ? bq[l * 384 + j] : (t == 1 ? bk[l * 384 + j] : bv[l * 384 + j]);
    out[i] = v;
}

// -------------------- split-precision MFMA GEMM (templated, proven R10) ------------
// MODEK 0: 3-term C = A_hi@W_hi + A_hi@W_lo + A_lo@W_hi ; A [M][2K], W [N][2K]; Kend=3K
// MODEK 2: 2-term C = A@(W_hi+W_lo)  (bf16-A x fp32-W)   ; A [M][K],  W [N][2K]; Kend=2K
// BIG=1: 256x128 tile, 8 waves. BIG=0: 128x128, 4 waves.
// 3-buffer LDS, 2-deep prefetch, counted vmcnt, raw s_barrier, setprio on MFMA.
template <int TAG, int BIG, int OMODE, int MODEK, int ACT>
__global__ __launch_bounds__(BIG ? 512 : 256) void gemm_bf16_kernel(
        const __hip_bfloat16* __restrict__ A2,
        const __hip_bfloat16* __restrict__ Wt2,
        const float* __restrict__ bias,
        void* __restrict__ outp,
        int N, int K, int nbx) {
    constexpr int BM = BIG ? 256 : 128;
    __shared__ __hip_bfloat16 As[3][BM * 32];
    __shared__ __hip_bfloat16 Bs[3][128 * 32];
    int t = threadIdx.x;
    int lane = t & 63, wv = t >> 6;
    int wm = wv >> 1, wn = wv & 1;

    int nwg = gridDim.x;
    int q8 = nwg >> 3, r8 = nwg & 7;
    int xcd = blockIdx.x & 7, off = blockIdx.x >> 3;
    int swz = (xcd < r8 ? xcd * (q8 + 1) : r8 * (q8 + 1) + (xcd - r8) * q8) + off;
    int bn = (swz % nbx) * 128;
    int bm = (swz / nbx) * BM;

    const int KstA = (MODEK == 2) ? K : 2 * K;
    const int KstW = 2 * K;
    const int Kend = (MODEK == 0) ? 3 * K : 2 * K;
    f32x4 acc[4][4] = {};

    int sr   = t >> 2;
    int sswz = (t & 3) ^ ((t >> 2) & 3) ^ ((t >> 4) & 3);
    const __hip_bfloat16* a_src = A2 + (size_t)(bm + sr) * KstA + sswz * 8;
    const __hip_bfloat16* b_src = Wt2 + (size_t)(bn + sr) * KstW + sswz * 8;

    int slotp = (lane >> 4) ^ (lane & 3) ^ ((lane >> 2) & 3);
    int aOff = (wm * 64 + (lane & 15)) * 32 + slotp * 8;
    int bOff = (wn * 64 + (lane & 15)) * 32 + slotp * 8;

#define STAGE(buf, ak, wk) do { \
        gload_lds16(a_src + (ak), &As[buf][wv * 512]); \
        gload_lds16(a_src + (size_t)(BM / 2) * KstA + (ak), &As[buf][(BM / 2) * 32 + wv * 512]); \
        gload_lds16(b_src + (wk), &Bs[buf][wv * 512]); \
        if (!BIG) gload_lds16(b_src + (size_t)64 * KstW + (wk), &Bs[buf][2048 + wv * 512]); \
    } while (0)

#define KOFFS(k0, ak, wk) do { \
        if (MODEK == 0) { ak = ((k0) < K) ? (k0) : (k0) - K; wk = ((k0) < 2 * K) ? (k0) : (k0) - 2 * K; } \
        else            { ak = ((k0) < K) ? (k0) : (k0) - K; wk = (k0); } \
    } while (0)

    int nt = Kend >> 5;
    {
        int ak, wk;
        KOFFS(0, ak, wk);
        STAGE(0, ak, wk);
        KOFFS(32, ak, wk);
        STAGE(1, ak, wk);
    }
    int c0 = 0, c1 = 1, c2 = 2;
    for (int ti = 0; ti < nt; ++ti) {
        if (ti + 2 < nt) {
            int k2 = (ti + 2) << 5;
            int ak, wk;
            KOFFS(k2, ak, wk);
            STAGE(c2, ak, wk);
            if (BIG) { VMW(6); } else { VMW(8); }
        } else if (ti + 2 == nt) {
            if (BIG) { VMW(3); } else { VMW(4); }
        } else {
            VMW(0);
        }
        __builtin_amdgcn_s_barrier();
        short8 af[4], bf[4];
        #pragma unroll
        for (int m = 0; m < 4; ++m) af[m] = *(const short8*)(&As[c0][aOff + m * 512]);
        #pragma unroll
        for (int n = 0; n < 4; ++n) bf[n] = *(const short8*)(&Bs[c0][bOff + n * 512]);
        __builtin_amdgcn_s_setprio(1);
        #pragma unroll
        for (int m = 0; m < 4; ++m)
            #pragma unroll
            for (int n = 0; n < 4; ++n)
                acc[m][n] = __builtin_amdgcn_mfma_f32_16x16x32_bf16(af[m], bf[n], acc[m][n], 0, 0, 0);
        __builtin_amdgcn_s_setprio(0);
        __builtin_amdgcn_s_barrier();
        int tmp = c0; c0 = c1; c1 = c2; c2 = tmp;
    }
#undef STAGE
#undef KOFFS

    int colBase = bn + wn * 64 + (lane & 15);
    int rowBase = bm + wm * 64 + (lane >> 4) * 4;
    const float c0f = 0.7978845608f;
    #pragma unroll
    for (int n = 0; n < 4; ++n) {
        int c = colBase + n * 16;
        float bvv = bias[c];
        #pragma unroll
        for (int m = 0; m < 4; ++m) {
            int r0 = rowBase + m * 16;
            #pragma unroll
            for (int r = 0; r < 4; ++r) {
                float v = acc[m][n][r] + bvv;
                if (ACT == 1) {
                    // gelu(v) = v*sigmoid(2u) == v*0.5*(1+tanh(u)); __expf form
                    float u = c0f * (v + 0.044715f * v * v * v);
                    v = v / (1.0f + __expf(-2.0f * u));
                }
                size_t row = (size_t)(r0 + r);
                if (OMODE == 0) {
                    ((float*)outp)[row * N + c] = v;
                } else {
                    ((__hip_bfloat16*)outp)[row * N + c] = __float2bfloat16(v);
                }
            }
        }
    }
}

// ---------------- MFMA attention per (b, nh) ----------------------------------------
__global__ __launch_bounds__(256) void attn_kernel(const __hip_bfloat16* __restrict__ qkvP,
        const int* __restrict__ x, __hip_bfloat16* __restrict__ a2) {
    __shared__ unsigned short qs[112][32];
    __shared__ unsigned short ks[128][32];
    __shared__ unsigned short vst[32][136];
    __shared__ unsigned short ps[112][136];
    __shared__ int xb[128];
    int t = threadIdx.x;
    int lane = t & 63, wv = t >> 6;
    int b = blockIdx.x / NH_;
    int nh = blockIdx.x % NH_;
    const __hip_bfloat16* base = qkvP + (size_t)b * L_ * QKVN;

    for (int i = t; i < 576; i += 256) {
        int d = i / 18, w = i % 18;
        ((int*)vst)[d * 68 + 50 + w] = 0;
    }
    for (int i = t; i < 128; i += 256) xb[i] = (i < L_) ? x[b * L_ + i] : 0;

    {
        int r16 = lane >> 2, s = lane & 3;
        for (int i = wv; i < 7; i += 4) {
            int row = i * 16 + r16;
            int sp = s ^ (row & 3) ^ ((row >> 2) & 3);
            gload_lds16(base + (size_t)row * QKVN + nh * 32 + sp * 8, &qs[i * 16][0]);
        }
        for (int i = wv; i < 8; i += 4) {
            int row = i * 16 + r16;
            int sp = s ^ (row & 3) ^ ((row >> 2) & 3);
            gload_lds16(base + (size_t)row * QKVN + 384 + nh * 32 + sp * 8, &ks[i * 16][0]);
        }
    }
    if (t < 200) {
        int kv = t >> 1, d0 = (t & 1) * 16;
        const __hip_bfloat16* vsrc = base + (size_t)kv * QKVN + 768 + nh * 32 + d0;
        short8 v0 = *(const short8*)vsrc;
        short8 v1 = *(const short8*)(vsrc + 8);
        #pragma unroll
        for (int j = 0; j < 8; ++j) {
            vst[d0 + j][kv]     = (unsigned short)v0[j];
            vst[d0 + 8 + j][kv] = (unsigned short)v1[j];
        }
    }
    __syncthreads();

    const float scale = 1.0f / sqrtf((float)H_);
    int n = lane & 15, g = lane >> 4;

    for (int rt = wv; rt < 7; rt += 4) {
        int arow = rt * 16 + n;
        int asp = (g ^ (arow & 3) ^ ((arow >> 2) & 3)) * 8;
        short8 aq = *(const short8*)&qs[arow][asp];
        f32x4 s8[8];
        #pragma unroll
        for (int ct = 0; ct < 8; ++ct) {
            int brow = ct * 16 + n;
            int bsp = (g ^ (brow & 3) ^ ((brow >> 2) & 3)) * 8;
            short8 bk = *(const short8*)&ks[brow][bsp];
            f32x4 z = {0.0f, 0.0f, 0.0f, 0.0f};
            s8[ct] = __builtin_amdgcn_mfma_f32_16x16x32_bf16(aq, bk, z, 0, 0, 0);
        }
        #pragma unroll
        for (int ct = 0; ct < 8; ++ct) {
            int col = ct * 16 + n;
            int xv = xb[col];
            #pragma unroll
            for (int r = 0; r < 4; ++r) {
                float v = s8[ct][r] * scale;
                v = (xv == 0) ? -1e10f : v;
                v = (col >= L_) ? -INFINITY : v;
                s8[ct][r] = v;
            }
        }
        float sm[4];
        #pragma unroll
        for (int r = 0; r < 4; ++r) {
            float m = s8[0][r];
            #pragma unroll
            for (int ct = 1; ct < 8; ++ct) m = fmaxf(m, s8[ct][r]);
            m = fmaxf(m, __shfl_xor(m, 1, 16));
            m = fmaxf(m, __shfl_xor(m, 2, 16));
            m = fmaxf(m, __shfl_xor(m, 4, 16));
            m = fmaxf(m, __shfl_xor(m, 8, 16));
            float s = 0.0f;
            #pragma unroll
            for (int ct = 0; ct < 8; ++ct) {
                float p = __expf(s8[ct][r] - m);
                s8[ct][r] = p;
                s += p;
            }
            s += __shfl_xor(s, 1, 16);
            s += __shfl_xor(s, 2, 16);
            s += __shfl_xor(s, 4, 16);
            s += __shfl_xor(s, 8, 16);
            sm[r] = s;
        }
        int prow = rt * 16 + g * 4;
        #pragma unroll
        for (int ct = 0; ct < 8; ++ct) {
            int col = ct * 16 + n;
            #pragma unroll
            for (int r = 0; r < 4; ++r)
                ps[prow + r][col] = f2b(s8[ct][r]);
        }
        f32x4 o0 = {0.0f, 0.0f, 0.0f, 0.0f}, o1 = o0;
        #pragma unroll
        for (int kt = 0; kt < 4; ++kt) {
            short8 pa = *(const short8*)&ps[rt * 16 + n][kt * 32 + g * 8];
            short8 b0 = *(const short8*)&vst[n][kt * 32 + g * 8];
            short8 b1 = *(const short8*)&vst[16 + n][kt * 32 + g * 8];
            o0 = __builtin_amdgcn_mfma_f32_16x16x32_bf16(pa, b0, o0, 0, 0, 0);
            o1 = __builtin_amdgcn_mfma_f32_16x16x32_bf16(pa, b1, o1, 0, 0, 0);
        }
        #pragma unroll
        for (int r = 0; r < 4; ++r) {
            int lrow = prow + r;
            if (lrow < L_) {
                size_t row = (size_t)b * L_ + lrow;
                float inv = 1.0f / sm[r];
                __hip_bfloat16 h, lo;
                float v0 = o0[r] * inv;
                split2(v0, h, lo);
                a2[row * (2 * H_) + nh * DH_ + n]      = h;
                a2[row * (2 * H_) + H_ + nh * DH_ + n] = lo;
                float v1 = o1[r] * inv;
                split2(v1, h, lo);
                a2[row * (2 * H_) + nh * DH_ + 16 + n]      = h;
                a2[row * (2 * H_) + H_ + nh * DH_ + 16 + n] = lo;
            }
        }
    }
}

// ---------------- fused residual + LayerNorm (scalar g,b; ddof=1) * nonpad ---------
template <int MODE>
__global__ __launch_bounds__(128) void ln_kernel(
        const float* __restrict__ Xf,
        const __hip_bfloat16* __restrict__ R2,
        const int* __restrict__ x,
        const float* __restrict__ gp, const float* __restrict__ bp, int layer,
        float* __restrict__ Yf,
        __hip_bfloat16* __restrict__ Y2,
        __hip_bfloat16* __restrict__ acc2) {
    int row = blockIdx.x;
    int tid = threadIdx.x;
    size_t b1 = (size_t)row * H_;
    size_t b2 = (size_t)row * (2 * H_);

    float v[3];
    #pragma unroll
    for (int j = 0; j < 3; ++j) {
        int f = tid + j * 128;
        float r = __bfloat162float(R2[b2 + f]) + __bfloat162float(R2[b2 + H_ + f]);
        v[j] = Xf[b1 + f] + r;
    }

    __shared__ float red[2];
    float s = v[0] + v[1] + v[2];
    #pragma unroll
    for (int off = 32; off > 0; off >>= 1) s += __shfl_down(s, off);
    if ((tid & 63) == 0) red[tid >> 6] = s;
    __syncthreads();
    float mu = (red[0] + red[1]) * (1.0f / 384.0f);
    __syncthreads();

    float d[3];
    float qq = 0.0f;
    #pragma unroll
    for (int j = 0; j < 3; ++j) { d[j] = v[j] - mu; qq += d[j] * d[j]; }
    #pragma unroll
    for (int off = 32; off > 0; off >>= 1) qq += __shfl_down(qq, off);
    if ((tid & 63) == 0) red[tid >> 6] = qq;
    __syncthreads();
    float var = (red[0] + red[1]) * (1.0f / 383.0f);
    float rstd = rsqrtf(var + 1e-8f);

    float g = gp[layer], bb = bp[layer];
    float np_ = (x[row] != 0) ? 1.0f : 0.0f;
    #pragma unroll
    for (int j = 0; j < 3; ++j) {
        int f = tid + j * 128;
        float y = (g * (d[j] * rstd) + bb) * np_;
        if (MODE == 0) {
            __hip_bfloat16 h, lo;
            split2(y, h, lo);
            Y2[b2 + f]      = h;
            Y2[b2 + H_ + f] = lo;
        } else {
            Yf[b1 + f] = y;
            float a = __bfloat162float(acc2[b2 + f]) + __bfloat162float(acc2[b2 + H_ + f]) + y;
            __hip_bfloat16 h, lo;
            split2(a, h, lo);
            acc2[b2 + f]      = h;
            acc2[b2 + H_ + f] = lo;
        }
    }
}

extern "C" void kernel_launch(void* const* d_in, const int* in_sizes, int n_in,
                              void* d_out, int out_size, void* d_ws, size_t ws_size,
                              hipStream_t stream) {
    const int*   x    = (const int*)d_in[0];
    const int*   seg  = (const int*)d_in[1];
    const float* tok  = (const float*)d_in[2];
    const float* sege = (const float*)d_in[3];
    const float* pos  = (const float*)d_in[4];
    const float* Wq   = (const float*)d_in[5];
    const float* bq   = (const float*)d_in[6];
    const float* Wk   = (const float*)d_in[7];
    const float* bk   = (const float*)d_in[8];
    const float* Wv   = (const float*)d_in[9];
    const float* bv   = (const float*)d_in[10];
    const float* Wo   = (const float*)d_in[11];
    const float* bo   = (const float*)d_in[12];
    const float* g1   = (const float*)d_in[13];
    const float* be1  = (const float*)d_in[14];
    const float* W1   = (const float*)d_in[15];
    const float* b1   = (const float*)d_in[16];
    const float* W2   = (const float*)d_in[17];
    const float* b2   = (const float*)d_in[18];
    const float* g2   = (const float*)d_in[19];
    const float* be2  = (const float*)d_in[20];

    char* p = (char*)d_ws;
    __hip_bfloat16* wT   = (__hip_bfloat16*)p; p += (size_t)NL_ * LW * 2;
    __hip_bfloat16* acc2 = (__hip_bfloat16*)p; p += 39321600;
    __hip_bfloat16* bE2  = (__hip_bfloat16*)p; p += 39321600;
    float* qkvb          = (float*)p;          p += 27648;
    char* pool           = p;
    __hip_bfloat16* qkvP = (__hip_bfloat16*)pool;
    __hip_bfloat16* bA2  = (__hip_bfloat16*)(pool + 58982400);
    float*          woF  = (float*)pool;
    __hip_bfloat16* f2   = (__hip_bfloat16*)pool;
    float* out = (float*)d_out;

    transpose_all_kernel<<<dim3(1728 * NL_), dim3(32, 8), 0, stream>>>(Wq, Wk, Wv, Wo, W1, W2, wT);
    bias_concat_kernel<<<dim3((NL_ * QKVN + 255) / 256), dim3(256), 0, stream>>>(bq, bk, bv, qkvb);
    embed_kernel<<<dim3((M_ * H_ + 255) / 256), dim3(256), 0, stream>>>(x, seg, tok, sege, pos, acc2);

    for (int l = 0; l < NL_; ++l) {
        const __hip_bfloat16* wTL = wT + (size_t)l * LW;
        const float* bol = bo + (size_t)l * H_;
        const float* b1l = b1 + (size_t)l * FF_;
        const float* b2l = b2 + (size_t)l * H_;

        // QKV (head-major cols), 3-term -> qkvP bf16 : BIG, 900 blocks
        gemm_bf16_kernel<0, 1, 2, 0, 0><<<dim3((QKVN / 128) * (M_ / 256)), dim3(512), 0, stream>>>(
            acc2, wTL + OFF_Q, qkvb + (size_t)l * QKVN, qkvP, QKVN, H_, QKVN / 128);
        // MFMA attention -> bA2 bf16x2
        attn_kernel<<<dim3(B_ * NH_), dim3(256), 0, stream>>>(qkvP, x, bA2);
        // Wo, 3-term (f32 output) -> woF : 128x128 (600 blocks)
        gemm_bf16_kernel<1, 0, 0, 0, 0><<<dim3((H_ / 128) * (M_ / 128)), dim3(256), 0, stream>>>(
            bA2, wTL + OFF_WO, bol, woF, H_, H_, H_ / 128);
        // LN1(woF + acc2) -> bE2
        ln_kernel<0><<<dim3(M_), dim3(128), 0, stream>>>(
            woF, acc2, x, g1, be1, l, nullptr, bE2, nullptr);
        // W1, 3-term + gelu -> f2 bf16 : BIG (R10-proven), 1200 blocks
        gemm_bf16_kernel<2, 1, 2, 0, 1><<<dim3((FF_ / 128) * (M_ / 256)), dim3(512), 0, stream>>>(
            bE2, wTL + OFF_W1, b1l, f2, FF_, H_, FF_ / 128);
        // W2, 2-term (bf16-A x fp32-grade-W) -> out f32 : 128x128, 600 blocks
        gemm_bf16_kernel<3, 0, 0, 2, 0><<<dim3((H_ / 128) * (M_ / 128)), dim3(256), 0, stream>>>(
            f2, wTL + OFF_W2, b2l, out, H_, FF_, H_ / 128);
        // LN2(out + bE2) -> out ; acc2 update
        ln_kernel<1><<<dim3(M_), dim3(128), 0, stream>>>(
            out, bE2, x, g2, be2, l, out, nullptr, acc2);
    }
}

// Round 18
// 2505.026 us; speedup vs baseline: 1.1386x; 1.0122x over previous
//
#include <hip/hip_runtime.h>
#include <hip/hip_bf16.h>
#include <math.h>

#define B_  256
#define L_  100
#define H_  384
#define NH_ 12
#define DH_ 32
#define NL_ 6
#define FF_ 1536
#define M_  (B_*L_)   // 25600 rows
#define QKVN 1152     // 3*H

// per-layer transposed bf16x2 weight layout within wT + l*LW (elements)
#define LW     3538944
#define OFF_Q  0
#define OFF_K  294912
#define OFF_V  589824
#define OFF_WO 884736
#define OFF_W1 1179648
#define OFF_W2 2359296

typedef __attribute__((ext_vector_type(8))) short short8;
typedef __attribute__((ext_vector_type(4))) float f32x4;

#define GLOBAL_AS __attribute__((address_space(1)))
#define LDS_AS    __attribute__((address_space(3)))

__device__ __forceinline__ void gload_lds16(const void* g, void* l) {
    __builtin_amdgcn_global_load_lds((const GLOBAL_AS void*)g, (LDS_AS void*)l, 16, 0, 0);
}

__device__ __forceinline__ void split2(float v, __hip_bfloat16& hi, __hip_bfloat16& lo) {
    hi = __float2bfloat16(v);
    lo = __float2bfloat16(v - __bfloat162float(hi));
}

__device__ __forceinline__ unsigned short f2b(float v) {
    __hip_bfloat16 h = __float2bfloat16(v);
    return *(unsigned short*)&h;
}

#define VMW(N) asm volatile("s_waitcnt vmcnt(" #N ")" ::: "memory")

// ---------------- embedding: acc2 = split(tok[x] + seg[s] + pos[l]) * nonpad -------
__global__ void embed_kernel(const int* __restrict__ x, const int* __restrict__ seg,
                             const float* __restrict__ tok, const float* __restrict__ sege,
                             const float* __restrict__ pos,
                             __hip_bfloat16* __restrict__ acc2) {
    int idx = blockIdx.x * blockDim.x + threadIdx.x;
    if (idx >= M_ * H_) return;
    int m = idx / H_;
    int f = idx - m * H_;
    int t = x[m];
    int s = seg[m];
    int l = m % L_;
    float v = tok[t * H_ + f] + sege[s * H_ + f] + pos[l * H_ + f];
    v = (t != 0) ? v : 0.0f;
    __hip_bfloat16 h, lo;
    split2(v, h, lo);
    acc2[(size_t)m * (2 * H_) + f]      = h;
    acc2[(size_t)m * (2 * H_) + H_ + f] = lo;
}

// ------ ALL-layers weight prep, hoisted (f32 -> bf16x2 [N][2K]), one launch --------
__global__ void transpose_all_kernel(const float* __restrict__ Wq, const float* __restrict__ Wk,
        const float* __restrict__ Wv, const float* __restrict__ Wo,
        const float* __restrict__ W1, const float* __restrict__ W2,
        __hip_bfloat16* __restrict__ wT) {
    __shared__ float tile[32][33];
    int l = blockIdx.x / 1728;
    int bid = blockIdx.x % 1728;
    const float* src;
    __hip_bfloat16* dst;
    int K, N, nx, tix, perm = 0;
    if (bid < 432) {               // Q,K,V: 3 x 144 tiles
        int m = bid / 144; tix = bid % 144;
        src = (m == 0) ? Wq : (m == 1 ? Wk : Wv);
        src += (size_t)l * H_ * H_;
        dst = wT + (size_t)l * LW + (m == 0 ? OFF_Q : (m == 1 ? OFF_K : OFF_V));
        K = 384; N = 384; nx = 12; perm = 1;
    } else if (bid < 576) {        // Wo: 144
        tix = bid - 432; src = Wo + (size_t)l * H_ * H_;
        dst = wT + (size_t)l * LW + OFF_WO; K = 384; N = 384; nx = 12;
    } else if (bid < 1152) {       // W1: 576
        tix = bid - 576; src = W1 + (size_t)l * H_ * FF_;
        dst = wT + (size_t)l * LW + OFF_W1; K = 384; N = 1536; nx = 48;
    } else {                       // W2: 576
        tix = bid - 1152; src = W2 + (size_t)l * FF_ * H_;
        dst = wT + (size_t)l * LW + OFF_W2; K = 1536; N = 384; nx = 12;
    }
    int n0 = (tix % nx) * 32, k0 = (tix / nx) * 32;
    int tx = threadIdx.x, ty = threadIdx.y;
    #pragma unroll
    for (int i = ty; i < 32; i += 8)
        tile[i][tx] = src[(size_t)(k0 + i) * N + (n0 + tx)];
    __syncthreads();
    #pragma unroll
    for (int i = ty; i < 32; i += 8) {
        float v = tile[tx][i];
        __hip_bfloat16 h, lo;
        split2(v, h, lo);
        int j = n0 + i;
        int jo = perm ? ((j % 12) * 32 + j / 12) : j;
        dst[(size_t)jo * (2 * K) + (k0 + tx)]     = h;
        dst[(size_t)jo * (2 * K) + K + (k0 + tx)] = lo;
    }
}

// bias concat with head-major permutation: out col j' = t*384 + nh*32 + d
__global__ void bias_concat_kernel(const float* __restrict__ bq, const float* __restrict__ bk,
                                   const float* __restrict__ bv, float* __restrict__ out) {
    int i = blockIdx.x * 256 + threadIdx.x;
    if (i >= NL_ * QKVN) return;
    int l = i / QKVN, jp = i - l * QKVN;
    int t = jp / 384, r = jp % 384;
    int h = r >> 5, d = r & 31;
    int j = d * 12 + h;  // original (interleaved) column
    float v = (t == 0) ? bq[l * 384 + j] : (t == 1 ? bk[l * 384 + j] : bv[l * 384 + j]);
    out[i] = v;
}

// -------------------- split-precision MFMA GEMM (templated, proven R10) ------------
// MODEK 0: 3-term C = A_hi@W_hi + A_hi@W_lo + A_lo@W_hi ; A [M][2K], W [N][2K]; Kend=3K
// MODEK 2: 2-term C = A@(W_hi+W_lo)  (bf16-A x fp32-W)   ; A [M][K],  W [N][2K]; Kend=2K
// BIG=1: 256x128 tile, 8 waves. BIG=0: 128x128, 4 waves.
// 3-buffer LDS, 2-deep prefetch, counted vmcnt, raw s_barrier, setprio on MFMA.
template <int TAG, int BIG, int OMODE, int MODEK, int ACT>
__global__ __launch_bounds__(BIG ? 512 : 256) void gemm_bf16_kernel(
        const __hip_bfloat16* __restrict__ A2,
        const __hip_bfloat16* __restrict__ Wt2,
        const float* __restrict__ bias,
        void* __restrict__ outp,
        int N, int K, int nbx) {
    constexpr int BM = BIG ? 256 : 128;
    __shared__ __hip_bfloat16 As[3][BM * 32];
    __shared__ __hip_bfloat16 Bs[3][128 * 32];
    int t = threadIdx.x;
    int lane = t & 63, wv = t >> 6;
    int wm = wv >> 1, wn = wv & 1;

    int nwg = gridDim.x;
    int q8 = nwg >> 3, r8 = nwg & 7;
    int xcd = blockIdx.x & 7, off = blockIdx.x >> 3;
    int swz = (xcd < r8 ? xcd * (q8 + 1) : r8 * (q8 + 1) + (xcd - r8) * q8) + off;
    int bn = (swz % nbx) * 128;
    int bm = (swz / nbx) * BM;

    const int KstA = (MODEK == 2) ? K : 2 * K;
    const int KstW = 2 * K;
    const int Kend = (MODEK == 0) ? 3 * K : 2 * K;
    f32x4 acc[4][4] = {};

    int sr   = t >> 2;
    int sswz = (t & 3) ^ ((t >> 2) & 3) ^ ((t >> 4) & 3);
    const __hip_bfloat16* a_src = A2 + (size_t)(bm + sr) * KstA + sswz * 8;
    const __hip_bfloat16* b_src = Wt2 + (size_t)(bn + sr) * KstW + sswz * 8;

    int slotp = (lane >> 4) ^ (lane & 3) ^ ((lane >> 2) & 3);
    int aOff = (wm * 64 + (lane & 15)) * 32 + slotp * 8;
    int bOff = (wn * 64 + (lane & 15)) * 32 + slotp * 8;

#define STAGE(buf, ak, wk) do { \
        gload_lds16(a_src + (ak), &As[buf][wv * 512]); \
        gload_lds16(a_src + (size_t)(BM / 2) * KstA + (ak), &As[buf][(BM / 2) * 32 + wv * 512]); \
        gload_lds16(b_src + (wk), &Bs[buf][wv * 512]); \
        if (!BIG) gload_lds16(b_src + (size_t)64 * KstW + (wk), &Bs[buf][2048 + wv * 512]); \
    } while (0)

#define KOFFS(k0, ak, wk) do { \
        if (MODEK == 0) { ak = ((k0) < K) ? (k0) : (k0) - K; wk = ((k0) < 2 * K) ? (k0) : (k0) - 2 * K; } \
        else            { ak = ((k0) < K) ? (k0) : (k0) - K; wk = (k0); } \
    } while (0)

    int nt = Kend >> 5;
    {
        int ak, wk;
        KOFFS(0, ak, wk);
        STAGE(0, ak, wk);
        KOFFS(32, ak, wk);
        STAGE(1, ak, wk);
    }
    int c0 = 0, c1 = 1, c2 = 2;
    for (int ti = 0; ti < nt; ++ti) {
        if (ti + 2 < nt) {
            int k2 = (ti + 2) << 5;
            int ak, wk;
            KOFFS(k2, ak, wk);
            STAGE(c2, ak, wk);
            if (BIG) { VMW(6); } else { VMW(8); }
        } else if (ti + 2 == nt) {
            if (BIG) { VMW(3); } else { VMW(4); }
        } else {
            VMW(0);
        }
        __builtin_amdgcn_s_barrier();
        short8 af[4], bf[4];
        #pragma unroll
        for (int m = 0; m < 4; ++m) af[m] = *(const short8*)(&As[c0][aOff + m * 512]);
        #pragma unroll
        for (int n = 0; n < 4; ++n) bf[n] = *(const short8*)(&Bs[c0][bOff + n * 512]);
        __builtin_amdgcn_s_setprio(1);
        #pragma unroll
        for (int m = 0; m < 4; ++m)
            #pragma unroll
            for (int n = 0; n < 4; ++n)
                acc[m][n] = __builtin_amdgcn_mfma_f32_16x16x32_bf16(af[m], bf[n], acc[m][n], 0, 0, 0);
        __builtin_amdgcn_s_setprio(0);
        __builtin_amdgcn_s_barrier();
        int tmp = c0; c0 = c1; c1 = c2; c2 = tmp;
    }
#undef STAGE
#undef KOFFS

    int colBase = bn + wn * 64 + (lane & 15);
    int rowBase = bm + wm * 64 + (lane >> 4) * 4;
    const float c0f = 0.7978845608f;
    #pragma unroll
    for (int n = 0; n < 4; ++n) {
        int c = colBase + n * 16;
        float bvv = bias[c];
        #pragma unroll
        for (int m = 0; m < 4; ++m) {
            int r0 = rowBase + m * 16;
            #pragma unroll
            for (int r = 0; r < 4; ++r) {
                float v = acc[m][n][r] + bvv;
                if (ACT == 1) {
                    // gelu(v) = v*sigmoid(2u) == v*0.5*(1+tanh(u)); __expf form
                    float u = c0f * (v + 0.044715f * v * v * v);
                    v = v / (1.0f + __expf(-2.0f * u));
                }
                size_t row = (size_t)(r0 + r);
                if (OMODE == 0) {
                    ((float*)outp)[row * N + c] = v;
                } else {
                    ((__hip_bfloat16*)outp)[row * N + c] = __float2bfloat16(v);
                }
            }
        }
    }
}

// ---------------- MFMA attention per (b, nh) ----------------------------------------
__global__ __launch_bounds__(256) void attn_kernel(const __hip_bfloat16* __restrict__ qkvP,
        const int* __restrict__ x, __hip_bfloat16* __restrict__ a2) {
    __shared__ unsigned short qs[112][32];
    __shared__ unsigned short ks[128][32];
    __shared__ unsigned short vst[32][136];
    __shared__ unsigned short ps[112][136];
    __shared__ int xb[128];
    int t = threadIdx.x;
    int lane = t & 63, wv = t >> 6;
    int b = blockIdx.x / NH_;
    int nh = blockIdx.x % NH_;
    const __hip_bfloat16* base = qkvP + (size_t)b * L_ * QKVN;

    for (int i = t; i < 576; i += 256) {
        int d = i / 18, w = i % 18;
        ((int*)vst)[d * 68 + 50 + w] = 0;
    }
    for (int i = t; i < 128; i += 256) xb[i] = (i < L_) ? x[b * L_ + i] : 0;

    {
        int r16 = lane >> 2, s = lane & 3;
        for (int i = wv; i < 7; i += 4) {
            int row = i * 16 + r16;
            int sp = s ^ (row & 3) ^ ((row >> 2) & 3);
            gload_lds16(base + (size_t)row * QKVN + nh * 32 + sp * 8, &qs[i * 16][0]);
        }
        for (int i = wv; i < 8; i += 4) {
            int row = i * 16 + r16;
            int sp = s ^ (row & 3) ^ ((row >> 2) & 3);
            gload_lds16(base + (size_t)row * QKVN + 384 + nh * 32 + sp * 8, &ks[i * 16][0]);
        }
    }
    if (t < 200) {
        int kv = t >> 1, d0 = (t & 1) * 16;
        const __hip_bfloat16* vsrc = base + (size_t)kv * QKVN + 768 + nh * 32 + d0;
        short8 v0 = *(const short8*)vsrc;
        short8 v1 = *(const short8*)(vsrc + 8);
        #pragma unroll
        for (int j = 0; j < 8; ++j) {
            vst[d0 + j][kv]     = (unsigned short)v0[j];
            vst[d0 + 8 + j][kv] = (unsigned short)v1[j];
        }
    }
    __syncthreads();

    const float scale = 1.0f / sqrtf((float)H_);
    int n = lane & 15, g = lane >> 4;

    for (int rt = wv; rt < 7; rt += 4) {
        int arow = rt * 16 + n;
        int asp = (g ^ (arow & 3) ^ ((arow >> 2) & 3)) * 8;
        short8 aq = *(const short8*)&qs[arow][asp];
        f32x4 s8[8];
        #pragma unroll
        for (int ct = 0; ct < 8; ++ct) {
            int brow = ct * 16 + n;
            int bsp = (g ^ (brow & 3) ^ ((brow >> 2) & 3)) * 8;
            short8 bk = *(const short8*)&ks[brow][bsp];
            f32x4 z = {0.0f, 0.0f, 0.0f, 0.0f};
            s8[ct] = __builtin_amdgcn_mfma_f32_16x16x32_bf16(aq, bk, z, 0, 0, 0);
        }
        #pragma unroll
        for (int ct = 0; ct < 8; ++ct) {
            int col = ct * 16 + n;
            int xv = xb[col];
            #pragma unroll
            for (int r = 0; r < 4; ++r) {
                float v = s8[ct][r] * scale;
                v = (xv == 0) ? -1e10f : v;
                v = (col >= L_) ? -INFINITY : v;
                s8[ct][r] = v;
            }
        }
        float sm[4];
        #pragma unroll
        for (int r = 0; r < 4; ++r) {
            float m = s8[0][r];
            #pragma unroll
            for (int ct = 1; ct < 8; ++ct) m = fmaxf(m, s8[ct][r]);
            m = fmaxf(m, __shfl_xor(m, 1, 16));
            m = fmaxf(m, __shfl_xor(m, 2, 16));
            m = fmaxf(m, __shfl_xor(m, 4, 16));
            m = fmaxf(m, __shfl_xor(m, 8, 16));
            float s = 0.0f;
            #pragma unroll
            for (int ct = 0; ct < 8; ++ct) {
                float p = __expf(s8[ct][r] - m);
                s8[ct][r] = p;
                s += p;
            }
            s += __shfl_xor(s, 1, 16);
            s += __shfl_xor(s, 2, 16);
            s += __shfl_xor(s, 4, 16);
            s += __shfl_xor(s, 8, 16);
            sm[r] = s;
        }
        int prow = rt * 16 + g * 4;
        #pragma unroll
        for (int ct = 0; ct < 8; ++ct) {
            int col = ct * 16 + n;
            #pragma unroll
            for (int r = 0; r < 4; ++r)
                ps[prow + r][col] = f2b(s8[ct][r]);
        }
        f32x4 o0 = {0.0f, 0.0f, 0.0f, 0.0f}, o1 = o0;
        #pragma unroll
        for (int kt = 0; kt < 4; ++kt) {
            short8 pa = *(const short8*)&ps[rt * 16 + n][kt * 32 + g * 8];
            short8 b0 = *(const short8*)&vst[n][kt * 32 + g * 8];
            short8 b1 = *(const short8*)&vst[16 + n][kt * 32 + g * 8];
            o0 = __builtin_amdgcn_mfma_f32_16x16x32_bf16(pa, b0, o0, 0, 0, 0);
            o1 = __builtin_amdgcn_mfma_f32_16x16x32_bf16(pa, b1, o1, 0, 0, 0);
        }
        #pragma unroll
        for (int r = 0; r < 4; ++r) {
            int lrow = prow + r;
            if (lrow < L_) {
                size_t row = (size_t)b * L_ + lrow;
                float inv = 1.0f / sm[r];
                __hip_bfloat16 h, lo;
                float v0 = o0[r] * inv;
                split2(v0, h, lo);
                a2[row * (2 * H_) + nh * DH_ + n]      = h;
                a2[row * (2 * H_) + H_ + nh * DH_ + n] = lo;
                float v1 = o1[r] * inv;
                split2(v1, h, lo);
                a2[row * (2 * H_) + nh * DH_ + 16 + n]      = h;
                a2[row * (2 * H_) + H_ + nh * DH_ + 16 + n] = lo;
            }
        }
    }
}

// ---------------- fused residual + LayerNorm (scalar g,b; ddof=1) * nonpad ---------
// MODE 0 (LN1): Y -> Y2 (bf16x2)
// MODE 1 (LN2, last layer): Y -> Yf (f32, d_out) ; acc2 = split(recon(acc2) + Y)
// MODE 2 (LN2, inner layers): acc2 update ONLY (Yf store is dead: W2 of the next
//         layer fully overwrites d_out before anything reads it)
template <int MODE>
__global__ __launch_bounds__(128) void ln_kernel(
        const float* __restrict__ Xf,
        const __hip_bfloat16* __restrict__ R2,
        const int* __restrict__ x,
        const float* __restrict__ gp, const float* __restrict__ bp, int layer,
        float* __restrict__ Yf,
        __hip_bfloat16* __restrict__ Y2,
        __hip_bfloat16* __restrict__ acc2) {
    int row = blockIdx.x;
    int tid = threadIdx.x;
    size_t b1 = (size_t)row * H_;
    size_t b2 = (size_t)row * (2 * H_);

    float v[3];
    #pragma unroll
    for (int j = 0; j < 3; ++j) {
        int f = tid + j * 128;
        float r = __bfloat162float(R2[b2 + f]) + __bfloat162float(R2[b2 + H_ + f]);
        v[j] = Xf[b1 + f] + r;
    }

    __shared__ float red[2];
    float s = v[0] + v[1] + v[2];
    #pragma unroll
    for (int off = 32; off > 0; off >>= 1) s += __shfl_down(s, off);
    if ((tid & 63) == 0) red[tid >> 6] = s;
    __syncthreads();
    float mu = (red[0] + red[1]) * (1.0f / 384.0f);
    __syncthreads();

    float d[3];
    float qq = 0.0f;
    #pragma unroll
    for (int j = 0; j < 3; ++j) { d[j] = v[j] - mu; qq += d[j] * d[j]; }
    #pragma unroll
    for (int off = 32; off > 0; off >>= 1) qq += __shfl_down(qq, off);
    if ((tid & 63) == 0) red[tid >> 6] = qq;
    __syncthreads();
    float var = (red[0] + red[1]) * (1.0f / 383.0f);
    float rstd = rsqrtf(var + 1e-8f);

    float g = gp[layer], bb = bp[layer];
    float np_ = (x[row] != 0) ? 1.0f : 0.0f;
    #pragma unroll
    for (int j = 0; j < 3; ++j) {
        int f = tid + j * 128;
        float y = (g * (d[j] * rstd) + bb) * np_;
        if (MODE == 0) {
            __hip_bfloat16 h, lo;
            split2(y, h, lo);
            Y2[b2 + f]      = h;
            Y2[b2 + H_ + f] = lo;
        } else {
            if (MODE == 1) Yf[b1 + f] = y;
            float a = __bfloat162float(acc2[b2 + f]) + __bfloat162float(acc2[b2 + H_ + f]) + y;
            __hip_bfloat16 h, lo;
            split2(a, h, lo);
            acc2[b2 + f]      = h;
            acc2[b2 + H_ + f] = lo;
        }
    }
}

extern "C" void kernel_launch(void* const* d_in, const int* in_sizes, int n_in,
                              void* d_out, int out_size, void* d_ws, size_t ws_size,
                              hipStream_t stream) {
    const int*   x    = (const int*)d_in[0];
    const int*   seg  = (const int*)d_in[1];
    const float* tok  = (const float*)d_in[2];
    const float* sege = (const float*)d_in[3];
    const float* pos  = (const float*)d_in[4];
    const float* Wq   = (const float*)d_in[5];
    const float* bq   = (const float*)d_in[6];
    const float* Wk   = (const float*)d_in[7];
    const float* bk   = (const float*)d_in[8];
    const float* Wv   = (const float*)d_in[9];
    const float* bv   = (const float*)d_in[10];
    const float* Wo   = (const float*)d_in[11];
    const float* bo   = (const float*)d_in[12];
    const float* g1   = (const float*)d_in[13];
    const float* be1  = (const float*)d_in[14];
    const float* W1   = (const float*)d_in[15];
    const float* b1   = (const float*)d_in[16];
    const float* W2   = (const float*)d_in[17];
    const float* b2   = (const float*)d_in[18];
    const float* g2   = (const float*)d_in[19];
    const float* be2  = (const float*)d_in[20];

    char* p = (char*)d_ws;
    __hip_bfloat16* wT   = (__hip_bfloat16*)p; p += (size_t)NL_ * LW * 2;
    __hip_bfloat16* acc2 = (__hip_bfloat16*)p; p += 39321600;
    __hip_bfloat16* bE2  = (__hip_bfloat16*)p; p += 39321600;
    float* qkvb          = (float*)p;          p += 27648;
    char* pool           = p;
    __hip_bfloat16* qkvP = (__hip_bfloat16*)pool;
    __hip_bfloat16* bA2  = (__hip_bfloat16*)(pool + 58982400);
    float*          woF  = (float*)pool;
    __hip_bfloat16* f2   = (__hip_bfloat16*)pool;
    float* out = (float*)d_out;

    transpose_all_kernel<<<dim3(1728 * NL_), dim3(32, 8), 0, stream>>>(Wq, Wk, Wv, Wo, W1, W2, wT);
    bias_concat_kernel<<<dim3((NL_ * QKVN + 255) / 256), dim3(256), 0, stream>>>(bq, bk, bv, qkvb);
    embed_kernel<<<dim3((M_ * H_ + 255) / 256), dim3(256), 0, stream>>>(x, seg, tok, sege, pos, acc2);

    for (int l = 0; l < NL_; ++l) {
        const __hip_bfloat16* wTL = wT + (size_t)l * LW;
        const float* bol = bo + (size_t)l * H_;
        const float* b1l = b1 + (size_t)l * FF_;
        const float* b2l = b2 + (size_t)l * H_;

        // QKV (head-major cols), 3-term -> qkvP bf16 : BIG, 900 blocks
        gemm_bf16_kernel<0, 1, 2, 0, 0><<<dim3((QKVN / 128) * (M_ / 256)), dim3(512), 0, stream>>>(
            acc2, wTL + OFF_Q, qkvb + (size_t)l * QKVN, qkvP, QKVN, H_, QKVN / 128);
        // MFMA attention -> bA2 bf16x2
        attn_kernel<<<dim3(B_ * NH_), dim3(256), 0, stream>>>(qkvP, x, bA2);
        // Wo, 3-term (f32 output) -> woF : 128x128 (600 blocks)
        gemm_bf16_kernel<1, 0, 0, 0, 0><<<dim3((H_ / 128) * (M_ / 128)), dim3(256), 0, stream>>>(
            bA2, wTL + OFF_WO, bol, woF, H_, H_, H_ / 128);
        // LN1(woF + acc2) -> bE2
        ln_kernel<0><<<dim3(M_), dim3(128), 0, stream>>>(
            woF, acc2, x, g1, be1, l, nullptr, bE2, nullptr);
        // W1, 3-term + gelu -> f2 bf16 : BIG (R10-proven), 1200 blocks
        gemm_bf16_kernel<2, 1, 2, 0, 1><<<dim3((FF_ / 128) * (M_ / 256)), dim3(512), 0, stream>>>(
            bE2, wTL + OFF_W1, b1l, f2, FF_, H_, FF_ / 128);
        // W2, 2-term (bf16-A x fp32-grade-W) -> out f32 : 128x128, 600 blocks
        gemm_bf16_kernel<3, 0, 0, 2, 0><<<dim3((H_ / 128) * (M_ / 128)), dim3(256), 0, stream>>>(
            f2, wTL + OFF_W2, b2l, out, H_, FF_, H_ / 128);
        // LN2: inner layers skip the dead d_out store (MODE 2); last layer writes it
        if (l < NL_ - 1) {
            ln_kernel<2><<<dim3(M_), dim3(128), 0, stream>>>(
                out, bE2, x, g2, be2, l, nullptr, nullptr, acc2);
        } else {
            ln_kernel<1><<<dim3(M_), dim3(128), 0, stream>>>(
                out, bE2, x, g2, be2, l, out, nullptr, acc2);
        }
    }
}